// Round 1
// baseline (587.587 us; speedup 1.0000x reference)
//
#include <hip/hip_runtime.h>

// VolAttn3d: B=1, N=4, C=16, D=64, H=128, W=128
// scores[n] = (1/4) * sum_c q[c]*k[n,c]   (per voxel)
// attn = softmax_n(scores)
// x[c] = sum_n attn[n]*v[n,c]
// out[o] = b[o] + sum_c w[o,c]*x[c]

constexpr int C = 16;
constexpr int N = 4;
constexpr int DHW = 64 * 128 * 128;  // 1048576 voxels, divisible by 4

__global__ __launch_bounds__(256) void volattn3d_kernel(
    const float* __restrict__ q,
    const float* __restrict__ k,
    const float* __restrict__ v,
    const float* __restrict__ w,   // (C_out=16, C_in=16) row-major
    const float* __restrict__ b,   // (16,)
    float* __restrict__ out)
{
    const int t = blockIdx.x * blockDim.x + threadIdx.x;  // float4 index
    if (t >= DHW / 4) return;
    const size_t s = (size_t)t * 4;  // voxel byte-group start (element offset)

    // ---- load q into registers (16 coalesced float4 streams) ----
    float4 qr[C];
#pragma unroll
    for (int c = 0; c < C; ++c) {
        qr[c] = *reinterpret_cast<const float4*>(q + (size_t)c * DHW + s);
    }

    // ---- scores[n] = 0.25 * sum_c q[c]*k[n,c] ----
    float4 sc[N];
#pragma unroll
    for (int n = 0; n < N; ++n) {
        float ax = 0.f, ay = 0.f, az = 0.f, aw = 0.f;
#pragma unroll
        for (int c = 0; c < C; ++c) {
            float4 kv = *reinterpret_cast<const float4*>(
                k + (size_t)(n * C + c) * DHW + s);
            ax = fmaf(qr[c].x, kv.x, ax);
            ay = fmaf(qr[c].y, kv.y, ay);
            az = fmaf(qr[c].z, kv.z, az);
            aw = fmaf(qr[c].w, kv.w, aw);
        }
        sc[n] = make_float4(ax * 0.25f, ay * 0.25f, az * 0.25f, aw * 0.25f);
    }

    // ---- softmax over n (4 elements), per vector component ----
    float4 m = sc[0];
#pragma unroll
    for (int n = 1; n < N; ++n) {
        m.x = fmaxf(m.x, sc[n].x);
        m.y = fmaxf(m.y, sc[n].y);
        m.z = fmaxf(m.z, sc[n].z);
        m.w = fmaxf(m.w, sc[n].w);
    }
    float4 sum = make_float4(0.f, 0.f, 0.f, 0.f);
#pragma unroll
    for (int n = 0; n < N; ++n) {
        sc[n].x = __expf(sc[n].x - m.x);
        sc[n].y = __expf(sc[n].y - m.y);
        sc[n].z = __expf(sc[n].z - m.z);
        sc[n].w = __expf(sc[n].w - m.w);
        sum.x += sc[n].x;
        sum.y += sc[n].y;
        sum.z += sc[n].z;
        sum.w += sc[n].w;
    }
    const float4 inv = make_float4(1.f / sum.x, 1.f / sum.y, 1.f / sum.z, 1.f / sum.w);
#pragma unroll
    for (int n = 0; n < N; ++n) {
        sc[n].x *= inv.x;
        sc[n].y *= inv.y;
        sc[n].z *= inv.z;
        sc[n].w *= inv.w;
    }

    // ---- x[c] = sum_n attn[n] * v[n,c] ----
    float4 x[C];
#pragma unroll
    for (int c = 0; c < C; ++c) {
        float ax = 0.f, ay = 0.f, az = 0.f, aw = 0.f;
#pragma unroll
        for (int n = 0; n < N; ++n) {
            float4 vv = *reinterpret_cast<const float4*>(
                v + (size_t)(n * C + c) * DHW + s);
            ax = fmaf(sc[n].x, vv.x, ax);
            ay = fmaf(sc[n].y, vv.y, ay);
            az = fmaf(sc[n].z, vv.z, az);
            aw = fmaf(sc[n].w, vv.w, aw);
        }
        x[c] = make_float4(ax, ay, az, aw);
    }

    // ---- out[o] = b[o] + sum_c w[o,c] * x[c]  (w/b are wave-uniform scalar loads) ----
#pragma unroll
    for (int o = 0; o < C; ++o) {
        const float bo = b[o];
        float ax = bo, ay = bo, az = bo, aw = bo;
#pragma unroll
        for (int c = 0; c < C; ++c) {
            const float wc = w[o * C + c];
            ax = fmaf(wc, x[c].x, ax);
            ay = fmaf(wc, x[c].y, ay);
            az = fmaf(wc, x[c].z, az);
            aw = fmaf(wc, x[c].w, aw);
        }
        *reinterpret_cast<float4*>(out + (size_t)o * DHW + s) =
            make_float4(ax, ay, az, aw);
    }
}

extern "C" void kernel_launch(void* const* d_in, const int* in_sizes, int n_in,
                              void* d_out, int out_size, void* d_ws, size_t ws_size,
                              hipStream_t stream) {
    const float* q = (const float*)d_in[0];
    const float* k = (const float*)d_in[1];
    const float* v = (const float*)d_in[2];
    const float* w = (const float*)d_in[3];
    const float* b = (const float*)d_in[4];
    float* out = (float*)d_out;

    const int threads = 256;
    const int total = DHW / 4;            // 262144 threads
    const int blocks = (total + threads - 1) / threads;  // 1024 blocks
    volattn3d_kernel<<<blocks, threads, 0, stream>>>(q, k, v, w, b, out);
}

// Round 4
// 571.649 us; speedup vs baseline: 1.0279x; 1.0279x over previous
//
#include <hip/hip_runtime.h>

// VolAttn3d: B=1, N=4, C=16, D=64, H=128, W=128
// scores[n] = (1/4) * sum_c q[c]*k[n,c]   (per voxel)
// attn = softmax_n(scores)
// x[c] = sum_n attn[n]*v[n,c]
// out[o] = b[o] + sum_c w[o,c]*x[c]
//
// R4: float2/thread (32 waves/CU grid), nontemporal stores via native
// clang vector type (HIP_vector_type struct is rejected by the builtin).

constexpr int C = 16;
constexpr int N = 4;
constexpr int DHW = 64 * 128 * 128;  // 1048576 voxels

typedef float v2f __attribute__((ext_vector_type(2)));

__global__ __launch_bounds__(256) void volattn3d_kernel(
    const float* __restrict__ q,
    const float* __restrict__ k,
    const float* __restrict__ v,
    const float* __restrict__ w,   // (C_out=16, C_in=16) row-major
    const float* __restrict__ b,   // (16,)
    float* __restrict__ out)
{
    const int t = blockIdx.x * blockDim.x + threadIdx.x;  // float2 index
    if (t >= DHW / 2) return;
    const size_t s = (size_t)t * 2;  // element offset

    // ---- load q into registers (16 coalesced 8B streams) ----
    v2f qr[C];
#pragma unroll
    for (int c = 0; c < C; ++c) {
        qr[c] = *reinterpret_cast<const v2f*>(q + (size_t)c * DHW + s);
    }

    // ---- scores[n] = 0.25 * sum_c q[c]*k[n,c] ----
    v2f sc[N];
#pragma unroll
    for (int n = 0; n < N; ++n) {
        float ax = 0.f, ay = 0.f;
#pragma unroll
        for (int c = 0; c < C; ++c) {
            v2f kv = *reinterpret_cast<const v2f*>(
                k + (size_t)(n * C + c) * DHW + s);
            ax = fmaf(qr[c].x, kv.x, ax);
            ay = fmaf(qr[c].y, kv.y, ay);
        }
        sc[n].x = ax * 0.25f;
        sc[n].y = ay * 0.25f;
    }

    // ---- softmax over n (4 elements), per component ----
    float mx = sc[0].x, my = sc[0].y;
#pragma unroll
    for (int n = 1; n < N; ++n) {
        mx = fmaxf(mx, sc[n].x);
        my = fmaxf(my, sc[n].y);
    }
    float sx = 0.f, sy = 0.f;
#pragma unroll
    for (int n = 0; n < N; ++n) {
        sc[n].x = __expf(sc[n].x - mx);
        sc[n].y = __expf(sc[n].y - my);
        sx += sc[n].x;
        sy += sc[n].y;
    }
    const float ix = 1.f / sx, iy = 1.f / sy;
#pragma unroll
    for (int n = 0; n < N; ++n) {
        sc[n].x *= ix;
        sc[n].y *= iy;
    }

    // ---- x[c] = sum_n attn[n] * v[n,c] ----
    v2f x[C];
#pragma unroll
    for (int c = 0; c < C; ++c) {
        float ax = 0.f, ay = 0.f;
#pragma unroll
        for (int n = 0; n < N; ++n) {
            v2f vv = *reinterpret_cast<const v2f*>(
                v + (size_t)(n * C + c) * DHW + s);
            ax = fmaf(sc[n].x, vv.x, ax);
            ay = fmaf(sc[n].y, vv.y, ay);
        }
        x[c].x = ax;
        x[c].y = ay;
    }

    // ---- out[o] = b[o] + sum_c w[o,c] * x[c]; nontemporal store ----
#pragma unroll
    for (int o = 0; o < C; ++o) {
        const float bo = b[o];
        float ax = bo, ay = bo;
#pragma unroll
        for (int c = 0; c < C; ++c) {
            const float wc = w[o * C + c];
            ax = fmaf(wc, x[c].x, ax);
            ay = fmaf(wc, x[c].y, ay);
        }
        v2f r;
        r.x = ax;
        r.y = ay;
        v2f* dst = reinterpret_cast<v2f*>(out + (size_t)o * DHW + s);
        __builtin_nontemporal_store(r, dst);
    }
}

extern "C" void kernel_launch(void* const* d_in, const int* in_sizes, int n_in,
                              void* d_out, int out_size, void* d_ws, size_t ws_size,
                              hipStream_t stream) {
    const float* q = (const float*)d_in[0];
    const float* k = (const float*)d_in[1];
    const float* v = (const float*)d_in[2];
    const float* w = (const float*)d_in[3];
    const float* b = (const float*)d_in[4];
    float* out = (float*)d_out;

    const int threads = 256;
    const int total = DHW / 2;            // 524288 threads
    const int blocks = (total + threads - 1) / threads;  // 2048 blocks
    volattn3d_kernel<<<blocks, threads, 0, stream>>>(q, k, v, w, b, out);
}